// Round 1
// baseline (41852.197 us; speedup 1.0000x reference)
//
#include <hip/hip_runtime.h>

#define KK 67
#define DIN 4
#define CLIPM 16
#define NEPOCH 5

#if __has_builtin(__builtin_amdgcn_exp2f)
__device__ __forceinline__ float ex2(float x) { return __builtin_amdgcn_exp2f(x); }
#else
__device__ __forceinline__ float ex2(float x) { return exp2f(x); }
#endif
#if __has_builtin(__builtin_amdgcn_rcpf)
__device__ __forceinline__ float frcp(float x) { return __builtin_amdgcn_rcpf(x); }
#else
__device__ __forceinline__ float frcp(float x) { return 1.0f / x; }
#endif

__device__ __forceinline__ float sigm(float x) {
    return frcp(1.0f + ex2(-1.4426950408889634f * x));
}
__device__ __forceinline__ float tanh_(float x) {
    return 1.0f - 2.0f * frcp(1.0f + ex2(2.8853900817779268f * x));
}

// ---------------- Phase 1: per-frame GRNN + projections (parallel over T) ----------------
__global__ __launch_bounds__(128) void grnn_kernel(
    const float* __restrict__ vid,
    const float* __restrict__ W1, const float* __restrict__ b1,
    const float* __restrict__ gw, const float* __restrict__ gb,
    const float* __restrict__ gWih, const float* __restrict__ gWhh,
    const float* __restrict__ gbih, const float* __restrict__ gbhh,
    const float* __restrict__ W2, const float* __restrict__ b2,
    float* __restrict__ q)
{
    const int f = blockIdx.x;
    const int t = threadIdx.x;
    const int k = t;
    __shared__ float sWih[256], sWhh[256], sb[32], sW1[32], sb1[8], sW2[64], sb2[8];
    __shared__ float Msum[8];
    for (int i = t; i < 256; i += 128) { sWih[i] = gWih[i]; sWhh[i] = gWhh[i]; }
    if (t < 32) sb[t] = gbih[t] + gbhh[t];
    if (t < 32) sW1[t] = W1[t];
    if (t < 8)  sb1[t] = b1[t];
    if (t < 64) sW2[t] = W2[t];
    if (t < 8)  sb2[t] = b2[t];
    __syncthreads();

    const bool act = (k < KK);
    float R[8], S[8], gwl[8], gbl[8];
    if (act) {
        const float* vp = vid + ((size_t)f * KK + k) * DIN;
        const float v0 = vp[0], v1 = vp[1], v2 = vp[2], v3 = vp[3];
#pragma unroll
        for (int j = 0; j < 8; ++j) {
            R[j] = sb1[j] + sW1[j*4+0]*v0 + sW1[j*4+1]*v1 + sW1[j*4+2]*v2 + sW1[j*4+3]*v3;
            S[j] = 0.0f;
            gwl[j] = gw[k*8 + j];
            gbl[j] = gb[k*8 + j];
        }
    }
    for (int e = 0; e < NEPOCH; ++e) {
        if (t < 8) Msum[t] = 0.0f;
        __syncthreads();
        float per[8];
        if (act) {
#pragma unroll
            for (int j = 0; j < 8; ++j) { per[j] = gwl[j]*S[j] + gbl[j]; atomicAdd(&Msum[j], per[j]); }
        }
        __syncthreads();
        if (act) {
            float M[8];
#pragma unroll
            for (int j = 0; j < 8; ++j) M[j] = Msum[j] - per[j];
            float gv[32];
#pragma unroll
            for (int gg = 0; gg < 32; ++gg) {
                float a = sb[gg];
#pragma unroll
                for (int j = 0; j < 8; ++j)
                    a = fmaf(R[j], sWih[gg*8+j], fmaf(M[j], sWhh[gg*8+j], a));
                gv[gg] = a;
            }
#pragma unroll
            for (int j = 0; j < 8; ++j) {
                // lstm_cell(x=lastR, h=M, c=lastS): c2 = sig(f)*c + sig(i)*tanh(g); h2 = sig(o)*tanh(c2)
                float c2 = sigm(gv[8+j]) * S[j] + sigm(gv[j]) * tanh_(gv[16+j]);
                float h2 = sigm(gv[24+j]) * tanh_(c2);
                R[j] += S[j];   // updateRelation uses OLD lastS
                S[j] = h2;
            }
        }
        __syncthreads();
    }
    if (act) {
        float* qp = q + ((size_t)f * KK + k) * 8;
#pragma unroll
        for (int jo = 0; jo < 8; ++jo) {
            float a = sb2[jo];
#pragma unroll
            for (int j = 0; j < 8; ++j) a = fmaf(fmaxf(R[j], 0.0f), sW2[jo*8+j], a);
            qp[jo] = a;
        }
    }
}

// ---------------- Phase 2: two skip-LSTM chains, wavefront over 137k positions ----------------
// Block 0 = P chain (input q[u], writes HP at offset 0)
// Block 1 = V chain (input q[u]-q[u-67], writes HV at offset N*64)
// One wave (64 lanes) per block. lane = l*8+s: layer l, dim s, gates i/f/g/o for (l,s).
__global__ __launch_bounds__(64) void slstm_kernel(
    const float* __restrict__ q,
    const float* __restrict__ pWih, const float* __restrict__ pWhh,
    const float* __restrict__ pbih, const float* __restrict__ pbhh,
    const float* __restrict__ vWih, const float* __restrict__ vWhh,
    const float* __restrict__ vbih, const float* __restrict__ vbhh,
    float* __restrict__ out, int U, int N)
{
    const int lane = threadIdx.x;
    const int l = lane >> 3, s = lane & 7;
    const int isV = blockIdx.x;
    const float* Wih = isV ? vWih : pWih;
    const float* Whh = isV ? vWhh : pWhh;
    const float* bi  = isV ? vbih : pbih;
    const float* bh  = isV ? vbhh : pbhh;
    float* ob = out + (size_t)isV * (size_t)N * 64;

    float wih[4][8], whh[4][8], bias[4];
#pragma unroll
    for (int g2 = 0; g2 < 4; ++g2) {
        const int row = l*32 + g2*8 + s;
#pragma unroll
        for (int j = 0; j < 8; ++j) {
            wih[g2][j] = Wih[row*8 + j];
            whh[g2][j] = Whh[row*8 + j];
        }
        bias[g2] = bi[row] + bh[row];
    }

    // LDS exchange:
    //   hS[l*8+j]   : replicated h-state of layer l
    //   yS[0..7]    : injected layer-0 input for next diagonal (q-based)
    //   yS[8+lane]  : skip-output y of lane (read by layer l+1 as yS[(l+1)*8+j])
    //   yS[80..143] : dump area for non-group-0 inject writes (branchless)
    __shared__ __align__(16) float hS[64];
    __shared__ __align__(16) float yS[160];
    hS[lane] = 0.0f;
    yS[8 + lane] = 0.0f;
    yS[80 + lane] = 0.0f;
    if (lane < 8) yS[lane] = q[lane];   // x for u=0 (V: u<67 so no subtract)
    asm volatile("" ::: "memory");

    float c = 0.0f, Hm = 0.0f, Hc = 0.0f;
    int m = -l, cc = -l, n = 0;
    const int BND = CLIPM * KK - 1;     // 1071
    const int maxu = U - 1;

    // 4-deep register prefetch ring for q[u] (and q[u-67] for V). All lanes
    // load lane-s component -> 32B coalesced; only group 0 consumes.
    float ra[4], rb[4];
#pragma unroll
    for (int i = 1; i <= 4; ++i) {
        int u = i > maxu ? maxu : i;
        ra[i & 3] = q[u*8 + s];
        int ub = u - KK; if (ub < 0) ub = 0;
        rb[i & 3] = q[ub*8 + s];
    }

    auto step = [&](int d, int sl) {
        float x[8], h[8];
#pragma unroll
        for (int j = 0; j < 8; ++j) { x[j] = yS[l*8 + j]; h[j] = hS[l*8 + j]; }
        const float xown = yS[lane];
        float a0 = bias[0], a1 = bias[1], a2 = bias[2], a3 = bias[3];
#pragma unroll
        for (int j = 0; j < 8; ++j) {
            a0 = fmaf(x[j], wih[0][j], a0);
            a1 = fmaf(x[j], wih[1][j], a1);
            a2 = fmaf(x[j], wih[2][j], a2);
            a3 = fmaf(x[j], wih[3][j], a3);
            a0 = fmaf(h[j], whh[0][j], a0);
            a1 = fmaf(h[j], whh[1][j], a1);
            a2 = fmaf(h[j], whh[2][j], a2);
            a3 = fmaf(h[j], whh[3][j], a3);
        }
        const float ig = sigm(a0), fg = sigm(a1), gt = tanh_(a2), og = sigm(a3);
        const float c2 = fg * c + ig * gt;
        const float h2 = og * tanh_(c2);
        const bool act = (cc >= 0) && (cc < U);
        const bool bnd = act && (m == BND);
        const float HmN = Hm + h2, HcN = Hc + c2;
        const float hprop = bnd ? HmN : h2;   // state reset to accumulator at clip end
        c = act ? (bnd ? HcN : c2) : c;
        if (bnd) ob[(size_t)n * 64 + lane] = HmN;
        Hm = bnd ? HmN : Hm;
        Hc = bnd ? HcN : Hc;
        n += bnd ? 1 : 0;
        const float y = h2 + xown;            // skip connection (uses h2, not hprop)
        hS[lane] = act ? hprop : 0.0f;
        yS[8 + lane] = y;
        // inject layer-0 input for next diagonal (u = d+1)
        const int uN = d + 1;
        const float qc = ra[sl] - ((isV && uN >= KK) ? rb[sl] : 0.0f);
        const int wadr = (l == 0) ? s : (80 + lane);
        yS[wadr] = qc;
        // refill ring slot with u = d+5
        int u5 = d + 5; if (u5 > maxu) u5 = maxu;
        ra[sl] = q[u5*8 + s];
        int ub = u5 - KK; if (ub < 0) ub = 0;
        rb[sl] = q[ub*8 + s];
        m = (m == BND) ? 0 : (m + 1);
        ++cc;
        asm volatile("" ::: "memory");  // keep cross-lane LDS write->read ordering
    };

    const int Dtot = U + 8;   // U multiple of 4 (1072*N), +8 drains layers 1..7
    for (int d = 0; d < Dtot; d += 4) {
        step(d + 0, 1);
        step(d + 1, 2);
        step(d + 2, 3);
        step(d + 3, 0);
    }
}

extern "C" void kernel_launch(void* const* d_in, const int* in_sizes, int n_in,
                              void* d_out, int out_size, void* d_ws, size_t ws_size,
                              hipStream_t stream)
{
    const float* vid  = (const float*)d_in[0];
    const float* W1   = (const float*)d_in[1];
    const float* b1   = (const float*)d_in[2];
    const float* gw   = (const float*)d_in[3];
    const float* gb   = (const float*)d_in[4];
    const float* gWih = (const float*)d_in[5];
    const float* gWhh = (const float*)d_in[6];
    const float* gbih = (const float*)d_in[7];
    const float* gbhh = (const float*)d_in[8];
    const float* W2   = (const float*)d_in[9];
    const float* b2   = (const float*)d_in[10];
    const float* vWih = (const float*)d_in[11];
    const float* vWhh = (const float*)d_in[12];
    const float* vbih = (const float*)d_in[13];
    const float* vbhh = (const float*)d_in[14];
    const float* pWih = (const float*)d_in[15];
    const float* pWhh = (const float*)d_in[16];
    const float* pbih = (const float*)d_in[17];
    const float* pbhh = (const float*)d_in[18];

    const int T = in_sizes[0] / (KK * DIN);
    const int N = T / CLIPM;
    const int U = N * CLIPM * KK;
    float* q = (float*)d_ws;   // T*KK*8 floats = 4.4 MB

    grnn_kernel<<<dim3(T), dim3(128), 0, stream>>>(
        vid, W1, b1, gw, gb, gWih, gWhh, gbih, gbhh, W2, b2, q);
    slstm_kernel<<<dim3(2), dim3(64), 0, stream>>>(
        q, pWih, pWhh, pbih, pbhh, vWih, vWhh, vbih, vbhh, (float*)d_out, U, N);
}